// Round 9
// baseline (79.338 us; speedup 1.0000x reference)
//
#include <hip/hip_runtime.h>
#include <hip/hip_bf16.h>

#define LDIM 4096
#define BDIM 4
#define DDIM 64

typedef __attribute__((ext_vector_type(4))) float f32x4;
typedef __attribute__((ext_vector_type(8))) __bf16 bf16x8;
typedef __attribute__((ext_vector_type(4))) __bf16 bf16x4;

__device__ __forceinline__ bf16x8 cvt8(f32x4 a, f32x4 b) {
    bf16x8 r;
    r[0] = (__bf16)a[0]; r[1] = (__bf16)a[1]; r[2] = (__bf16)a[2]; r[3] = (__bf16)a[3];
    r[4] = (__bf16)b[0]; r[5] = (__bf16)b[1]; r[6] = (__bf16)b[2]; r[7] = (__bf16)b[3];
    return r;
}

// Fused: per-b GEMM C[b][l][m] = sum_d A[b][l][d] * Q[b][m][d] + bias,
// A = bf16(t0), Q = t1 . K^T, both produced in-block.
// 128x256 tile, 8 waves (2x4) of 64x64, K=64 (2 k-steps).
// vs round 5: __launch_bounds__(512,2) -> 256-VGPR budget (R5's (512,4)
// forced a 128-VGPR cap with ~120+ live regs -> suspected spill).
__global__ __launch_bounds__(512, 2) void fused_kernel(
    const float* __restrict__ t0,
    const float* __restrict__ t1,
    const float* __restrict__ kmat,
    const float* __restrict__ bias,
    float* __restrict__ out)
{
    __shared__ char smem[49152];   // A tile [0,16K), B(Q) tile [16K,48K)

    // chunked XCD swizzle: 2048 blocks, 8 XCDs, 256-contiguous per XCD
    const int bid0 = blockIdx.x;
    const int swz  = (bid0 & 7) * 256 + (bid0 >> 3);
    const int b    = swz >> 9;          // 512 tiles per b (32 tr x 16 tc)
    const int t    = swz & 511;
    const int tr   = t >> 4;
    const int tc   = t & 15;

    const int tid  = threadIdx.x;
    const int w    = tid >> 6;
    const int lane = tid & 63;
    const int wr   = w >> 2, wc = w & 3;    // 2x4 waves, 64x64 each
    const int lr   = lane & 15;
    const int lhi  = lane >> 4;

    char* As = smem;
    char* Bs = smem + 16384;

    // ---- Phase 0b issued first: A-panel global loads (no dependencies) ----
    const int r  = tid >> 2;            // 0..127
    const int cj = (tid & 3) * 2;       // bf16 16B-chunks {cj, cj+1}
    const float* sp = t0 + ((size_t)(tr * 128 + r) * BDIM + b) * DDIM + cj * 8;
    f32x4 a0 = *(const f32x4*)(sp + 0);
    f32x4 a1 = *(const f32x4*)(sp + 4);
    f32x4 a2 = *(const f32x4*)(sp + 8);
    f32x4 a3 = *(const f32x4*)(sp + 12);

    // ---- Phase 0a: Q-tile (256 rows x 64 d) -> Bs, 32 rows per wave ----
    // Q^T mfma: A-op = K rows (d), B-op = t1 rows (m) => C[row=d][col=m].
    {
        bf16x8 ka[4][2];
#pragma unroll
        for (int dt = 0; dt < 4; ++dt)
#pragma unroll
            for (int ks = 0; ks < 2; ++ks) {
                const float* kp = kmat + (size_t)(dt * 16 + lr) * DDIM + ks * 32 + lhi * 8;
                ka[dt][ks] = cvt8(*(const f32x4*)kp, *(const f32x4*)(kp + 4));
            }
        bf16x8 tb[2][2];
#pragma unroll
        for (int mt = 0; mt < 2; ++mt) {
            const int mloc = w * 32 + mt * 16 + lr;
            const float* tp = t1 + ((size_t)(tc * 256 + mloc) * BDIM + b) * DDIM;
#pragma unroll
            for (int ks = 0; ks < 2; ++ks)
                tb[mt][ks] = cvt8(*(const f32x4*)(tp + ks * 32 + lhi * 8),
                                  *(const f32x4*)(tp + ks * 32 + lhi * 8 + 4));
        }
        f32x4 qacc[4][2] = {};
#pragma unroll
        for (int ks = 0; ks < 2; ++ks)
#pragma unroll
            for (int dt = 0; dt < 4; ++dt)
#pragma unroll
                for (int mt = 0; mt < 2; ++mt)
                    qacc[dt][mt] = __builtin_amdgcn_mfma_f32_16x16x32_bf16(
                        ka[dt][ks], tb[mt][ks], qacc[dt][mt], 0, 0, 0);

        // lane holds Q[m = mt*16+lr][d = dt*16 + lhi*4 + j], j=0..3
        // XOR layout: chunk = (d>>3) ^ (m&7), byte-in-chunk = (d&7)*2
#pragma unroll
        for (int dt = 0; dt < 4; ++dt)
#pragma unroll
            for (int mt = 0; mt < 2; ++mt) {
                const int mloc = w * 32 + mt * 16 + lr;
                const int ch   = (dt * 2 + (lhi >> 1)) ^ (mloc & 7);
                bf16x4 qv;
                qv[0] = (__bf16)qacc[dt][mt][0];
                qv[1] = (__bf16)qacc[dt][mt][1];
                qv[2] = (__bf16)qacc[dt][mt][2];
                qv[3] = (__bf16)qacc[dt][mt][3];
                *(bf16x4*)(Bs + mloc * 128 + (ch << 4) + (lhi & 1) * 8) = qv;
            }
    }

    // ---- Phase 0b finish: A-panel fp32->bf16 -> As (XOR layout) ----
    *(bf16x8*)(As + r * 128 + ((cj ^ (r & 7)) << 4))       = cvt8(a0, a1);
    *(bf16x8*)(As + r * 128 + (((cj + 1) ^ (r & 7)) << 4)) = cvt8(a2, a3);
    __syncthreads();

    // ---- Main MFMA loop (R4 orientation) ----
    f32x4 acc[4][4] = {};
#pragma unroll
    for (int ks = 0; ks < 2; ++ks) {
        const int kx = ks * 4 + lhi;
        bf16x8 af[4], bq[4];
#pragma unroll
        for (int mi = 0; mi < 4; ++mi) {
            const int row = wr * 64 + mi * 16 + lr;
            af[mi] = *(const bf16x8*)(As + row * 128 + ((kx ^ (lr & 7)) << 4));
        }
#pragma unroll
        for (int ni = 0; ni < 4; ++ni) {
            const int row = wc * 64 + ni * 16 + lr;
            bq[ni] = *(const bf16x8*)(Bs + row * 128 + ((kx ^ (lr & 7)) << 4));
        }
#pragma unroll
        for (int mi = 0; mi < 4; ++mi)
#pragma unroll
            for (int ni = 0; ni < 4; ++ni)
                acc[mi][ni] = __builtin_amdgcn_mfma_f32_16x16x32_bf16(
                    af[mi], bq[ni], acc[mi][ni], 0, 0, 0);
    }

    // ---- Epilogue (R4 pattern: scalar stores, L2 merges fine) ----
    const float bs = bias[0];
    float* outp = out + (size_t)b * LDIM * LDIM;
    const int rowb = tr * 128 + wr * 64;
    const int colb = tc * 256 + wc * 64;
#pragma unroll
    for (int mi = 0; mi < 4; ++mi) {
#pragma unroll
        for (int ni = 0; ni < 4; ++ni) {
            const int col = colb + ni * 16 + lr;
#pragma unroll
            for (int j = 0; j < 4; ++j) {
                const int row = rowb + mi * 16 + lhi * 4 + j;
                outp[(size_t)row * LDIM + col] = acc[mi][ni][j] + bs;
            }
        }
    }
}

extern "C" void kernel_launch(void* const* d_in, const int* in_sizes, int n_in,
                              void* d_out, int out_size, void* d_ws, size_t ws_size,
                              hipStream_t stream) {
    const float* t0   = (const float*)d_in[0];
    const float* t1   = (const float*)d_in[1];
    const float* km   = (const float*)d_in[2];
    const float* bias = (const float*)d_in[3];
    float* out = (float*)d_out;

    fused_kernel<<<2048, 512, 0, stream>>>(t0, t1, km, bias, out);
}

// Round 10
// 53.918 us; speedup vs baseline: 1.4714x; 1.4714x over previous
//
#include <hip/hip_runtime.h>
#include <hip/hip_bf16.h>

#define LDIM 4096
#define BDIM 4
#define DDIM 64

typedef __attribute__((ext_vector_type(4))) float f32x4;
typedef __attribute__((ext_vector_type(8))) __bf16 bf16x8;

__device__ __forceinline__ bf16x8 cvt8(f32x4 a, f32x4 b) {
    bf16x8 r;
    r[0] = (__bf16)a[0]; r[1] = (__bf16)a[1]; r[2] = (__bf16)a[2]; r[3] = (__bf16)a[3];
    r[4] = (__bf16)b[0]; r[5] = (__bf16)b[1]; r[6] = (__bf16)b[2]; r[7] = (__bf16)b[3];
    return r;
}

__device__ __forceinline__ void gload_lds16(const void* g, void* l) {
    __builtin_amdgcn_global_load_lds(
        (const __attribute__((address_space(1))) void*)g,
        (__attribute__((address_space(3))) void*)l, 16, 0, 0);
}

// Stage 1 (MFMA-based): Q[b,m,d] = sum_e t1[m,b,e] * K[d,e] (bf16 out),
//                       A[b,m,d] = bf16(t0[m,b,d]).
// The compaction to per-b bf16 panels is what makes stage 2 cheap: fused
// variants (R5/R9) reading fp32 from the b-interleaved layout cost +25 us.
__global__ __launch_bounds__(256) void prep_kernel(
    const float* __restrict__ t0,
    const float* __restrict__ t1,
    const float* __restrict__ kmat,
    __hip_bfloat16* __restrict__ Abf,
    __hip_bfloat16* __restrict__ Qbf)
{
    const int tid  = threadIdx.x;
    const int w    = tid >> 6;
    const int lane = tid & 63;
    const int lr   = lane & 15;
    const int lhi  = lane >> 4;
    const int rbase = blockIdx.x * 64 + w * 16;

    f32x4 acc[4] = {{0.f,0.f,0.f,0.f},{0.f,0.f,0.f,0.f},{0.f,0.f,0.f,0.f},{0.f,0.f,0.f,0.f}};
#pragma unroll
    for (int ks = 0; ks < 2; ++ks) {
        const float* ap = t1 + (size_t)(rbase + lr) * DDIM + ks * 32 + lhi * 8;
        bf16x8 af = cvt8(*(const f32x4*)ap, *(const f32x4*)(ap + 4));
#pragma unroll
        for (int nt = 0; nt < 4; ++nt) {
            const float* bp = kmat + (size_t)(nt * 16 + lr) * DDIM + ks * 32 + lhi * 8;
            bf16x8 bq = cvt8(*(const f32x4*)bp, *(const f32x4*)(bp + 4));
            acc[nt] = __builtin_amdgcn_mfma_f32_16x16x32_bf16(af, bq, acc[nt], 0, 0, 0);
        }
    }
#pragma unroll
    for (int nt = 0; nt < 4; ++nt) {
#pragma unroll
        for (int j = 0; j < 4; ++j) {
            const int r = rbase + lhi * 4 + j;
            const int m = r >> 2, b = r & 3;
            Qbf[((size_t)(b * LDIM) + m) * DDIM + nt * 16 + lr] =
                __float2bfloat16(acc[nt][j]);
        }
    }

    {
        const int r2 = blockIdx.x * 64 + (tid >> 2);
        const int d0 = (tid & 3) * 16;
        const float* src = t0 + (size_t)r2 * DDIM + d0;
        f32x4 v0 = *(const f32x4*)(src + 0);
        f32x4 v1 = *(const f32x4*)(src + 4);
        f32x4 v2 = *(const f32x4*)(src + 8);
        f32x4 v3 = *(const f32x4*)(src + 12);
        const int m2 = r2 >> 2, b2 = r2 & 3;
        __hip_bfloat16* dst = Abf + ((size_t)(b2 * LDIM) + m2) * DDIM + d0;
        *(bf16x8*)dst       = cvt8(v0, v1);
        *(bf16x8*)(dst + 8) = cvt8(v2, v3);
    }
}

// Stage 2: per-b GEMM, C[b][l][m] = sum_d A[b][l][d] * Q[b][m][d] + bias.
// 128x256 tile per block, 8 waves (2x4) of 64x64. K=64 in LDS (XOR-swizzled).
// Direct scalar stores: R6 (NT), R7 (LDS-staged 1KB), R8 (dwordx4) all
// regressed -> L2 merges the 64B segments fine; this epilogue is optimal.
__global__ __launch_bounds__(512, 4) void gemm_kernel(
    const __hip_bfloat16* __restrict__ Abf,
    const __hip_bfloat16* __restrict__ Qbf,
    const float* __restrict__ bias,
    float* __restrict__ out)
{
    __shared__ char smem[49152];   // A tile [0,16K), B tile [16K,48K)

    // chunked XCD swizzle: 2048 blocks, 8 XCDs, 256-contiguous per XCD
    const int bid0 = blockIdx.x;
    const int swz  = (bid0 & 7) * 256 + (bid0 >> 3);
    const int b    = swz >> 9;          // 512 tiles per b (32 tr x 16 tc)
    const int t    = swz & 511;
    const int tr   = t >> 4;
    const int tc   = t & 15;

    const int tid  = threadIdx.x;
    const int w    = tid >> 6;
    const int lane = tid & 63;
    const int wr   = w >> 2, wc = w & 3;    // 2x4 waves, 64x64 each
    const int lr   = lane & 15;
    const int lhi  = lane >> 4;

    const char* Apan = (const char*)(Abf + ((size_t)b * LDIM + tr * 128) * DDIM);
    const char* Bpan = (const char*)(Qbf + ((size_t)b * LDIM + tc * 256) * DDIM);

#pragma unroll
    for (int i = 0; i < 2; ++i) {
        const int ci  = i * 8 + w;
        const int row = ci * 8 + (lane >> 3);
        const int so  = row * 128 + (((lane & 7) ^ (row & 7)) << 4);
        gload_lds16(Apan + so, smem + ci * 1024);
    }
#pragma unroll
    for (int i = 0; i < 4; ++i) {
        const int ci  = i * 8 + w;
        const int row = ci * 8 + (lane >> 3);
        const int so  = row * 128 + (((lane & 7) ^ (row & 7)) << 4);
        gload_lds16(Bpan + so, smem + 16384 + ci * 1024);
    }
    __syncthreads();

    const char* As = smem;
    const char* Bs = smem + 16384;

    f32x4 acc[4][4] = {};
#pragma unroll
    for (int ks = 0; ks < 2; ++ks) {
        const int kx = ks * 4 + lhi;
        bf16x8 af[4], bq[4];
#pragma unroll
        for (int mi = 0; mi < 4; ++mi) {
            const int row = wr * 64 + mi * 16 + lr;
            af[mi] = *(const bf16x8*)(As + row * 128 + ((kx ^ (lr & 7)) << 4));
        }
#pragma unroll
        for (int ni = 0; ni < 4; ++ni) {
            const int row = wc * 64 + ni * 16 + lr;
            bq[ni] = *(const bf16x8*)(Bs + row * 128 + ((kx ^ (lr & 7)) << 4));
        }
#pragma unroll
        for (int mi = 0; mi < 4; ++mi)
#pragma unroll
            for (int ni = 0; ni < 4; ++ni)
                acc[mi][ni] = __builtin_amdgcn_mfma_f32_16x16x32_bf16(
                    af[mi], bq[ni], acc[mi][ni], 0, 0, 0);
    }

    const float bs = bias[0];
    float* outp = out + (size_t)b * LDIM * LDIM;
    const int rowb = tr * 128 + wr * 64;
    const int colb = tc * 256 + wc * 64;
#pragma unroll
    for (int mi = 0; mi < 4; ++mi) {
#pragma unroll
        for (int ni = 0; ni < 4; ++ni) {
            const int col = colb + ni * 16 + lr;
#pragma unroll
            for (int j = 0; j < 4; ++j) {
                const int row = rowb + mi * 16 + lhi * 4 + j;
                outp[(size_t)row * LDIM + col] = acc[mi][ni][j] + bs;
            }
        }
    }
}

extern "C" void kernel_launch(void* const* d_in, const int* in_sizes, int n_in,
                              void* d_out, int out_size, void* d_ws, size_t ws_size,
                              hipStream_t stream) {
    const float* t0   = (const float*)d_in[0];
    const float* t1   = (const float*)d_in[1];
    const float* km   = (const float*)d_in[2];
    const float* bias = (const float*)d_in[3];
    float* out = (float*)d_out;

    __hip_bfloat16* Abf = (__hip_bfloat16*)d_ws;                 // [B][L][D] bf16 = 2 MB
    __hip_bfloat16* Qbf = Abf + (size_t)BDIM * LDIM * DDIM;      // [B][L][D] bf16 = 2 MB

    prep_kernel<<<256, 256, 0, stream>>>(t0, t1, km, Abf, Qbf);
    gemm_kernel<<<2048, 512, 0, stream>>>(Abf, Qbf, bias, out);
}